// Round 1
// baseline (84.470 us; speedup 1.0000x reference)
//
#include <hip/hip_runtime.h>
#include <math.h>

#define B_ 8
#define N_ 1024
#define C_ 512
#define K_ 20
#define M_ 64
#define R_ (B_*N_)   /* 8192 points */

/* ---- workspace layout (in floats) ---- */
#define WS_Y      0                       /* R_*128 : y (m<64) || z (m>=64) per point */
#define WS_HMAX   (R_*128)                /* R_*64 */
#define WS_HMIN   (WS_HMAX + R_*64)      /* R_*64 */
#define WS_P1     (WS_HMIN + R_*64)      /* 512 blocks * 128 (sum||sumsq) */
#define WS_SC1    (WS_P1 + 512*128)      /* 64 */
#define WS_SH1    (WS_SC1 + 64)          /* 64 */
#define WS_P2S    (WS_SH1 + 64)          /* 128*512 */
#define WS_P2Q    (WS_P2S + 128*512)     /* 128*512 */
#define WS_SC2    (WS_P2Q + 128*512)     /* 512 */
#define WS_SH2    (WS_SC2 + 512)         /* 512 */

/* ------------------------------------------------------------------ */
/* Pass 1: Y[r][j] ; j<64: dot(x[r], W1[j, 0:512]) ; j>=64: dot(x[r], W1[j-64, 512:1024]) */
__global__ __launch_bounds__(256) void k_yz(const float* __restrict__ x,
                                            const float* __restrict__ W1,
                                            float* __restrict__ Y) {
    __shared__ __align__(16) float sX[32][68];
    __shared__ __align__(16) float sW[128][68];
    const int t  = threadIdx.x;
    const int r0 = blockIdx.x * 32;
    const int tx = t & 15, ty = t >> 4;
    float acc[2][8];
#pragma unroll
    for (int a = 0; a < 2; ++a)
#pragma unroll
        for (int b = 0; b < 8; ++b) acc[a][b] = 0.f;

    for (int ks = 0; ks < 8; ++ks) {
        const int k0 = ks * 64;
#pragma unroll
        for (int i = 0; i < 2; ++i) {
            const int row = ty + 16 * i;
            *(float4*)&sX[row][tx * 4] =
                *(const float4*)&x[(size_t)(r0 + row) * C_ + k0 + tx * 4];
        }
#pragma unroll
        for (int i = 0; i < 8; ++i) {
            const int j = ty + 16 * i;
            const float* src = (j < 64)
                ? &W1[(size_t)j * 1024 + k0 + tx * 4]
                : &W1[(size_t)(j - 64) * 1024 + 512 + k0 + tx * 4];
            *(float4*)&sW[j][tx * 4] = *(const float4*)src;
        }
        __syncthreads();
#pragma unroll
        for (int k4 = 0; k4 < 16; ++k4) {
            const float4 a0 = *(const float4*)&sX[2 * ty][k4 * 4];
            const float4 a1 = *(const float4*)&sX[2 * ty + 1][k4 * 4];
#pragma unroll
            for (int jj = 0; jj < 8; ++jj) {
                const float4 bb = *(const float4*)&sW[tx + 16 * jj][k4 * 4];
                acc[0][jj] += a0.x * bb.x + a0.y * bb.y + a0.z * bb.z + a0.w * bb.w;
                acc[1][jj] += a1.x * bb.x + a1.y * bb.y + a1.z * bb.z + a1.w * bb.w;
            }
        }
        __syncthreads();
    }
#pragma unroll
    for (int rr = 0; rr < 2; ++rr)
#pragma unroll
        for (int jj = 0; jj < 8; ++jj)
            Y[(size_t)(r0 + 2 * ty + rr) * 128 + tx + 16 * jj] = acc[rr][jj];
}

/* ------------------------------------------------------------------ */
/* Pass 2: gather + h stats + per-point max/min over k.
   grid 512 blocks x 256 thr (4 waves); each wave handles 4 points; lane = channel m. */
__global__ __launch_bounds__(256) void k_gather(const float* __restrict__ Y,
                                                const int* __restrict__ idx,
                                                float* __restrict__ Hmax,
                                                float* __restrict__ Hmin,
                                                float* __restrict__ P1) {
    __shared__ float sRed[4][128];
    const int t = threadIdx.x;
    const int w = t >> 6, lane = t & 63;
    const int p0 = blockIdx.x * 16 + w * 4;
    float s_sum = 0.f, s_sq = 0.f;
#pragma unroll
    for (int i = 0; i < 4; ++i) {
        const int p = p0 + i;
        const int b = p >> 10;           /* N_=1024 */
        const float ys = Y[(size_t)p * 128 + lane];
        const float zs = Y[(size_t)p * 128 + 64 + lane];
        const float base = zs - ys;
        float hmx = -INFINITY, hmn = INFINITY;
        const int* ip = &idx[p * K_];
#pragma unroll
        for (int k = 0; k < K_; ++k) {
            const int j = ip[k];
            const float yg = Y[((size_t)(b * N_ + j)) * 128 + lane];
            const float h = yg + base;
            s_sum += h;
            s_sq  += h * h;
            hmx = fmaxf(hmx, h);
            hmn = fminf(hmn, h);
        }
        Hmax[(size_t)p * 64 + lane] = hmx;
        Hmin[(size_t)p * 64 + lane] = hmn;
    }
    sRed[w][lane]      = s_sum;
    sRed[w][64 + lane] = s_sq;
    __syncthreads();
    if (t < 128) {
        const float v = sRed[0][t] + sRed[1][t] + sRed[2][t] + sRed[3][t];
        P1[(size_t)blockIdx.x * 128 + t] = v;
    }
}

/* ------------------------------------------------------------------ */
__global__ void k_stats1(const float* __restrict__ P1,
                         const float* __restrict__ gamma1,
                         const float* __restrict__ beta1,
                         float* __restrict__ sc1,
                         float* __restrict__ sh1) {
    const int m = threadIdx.x;  /* 64 threads */
    float s = 0.f, q = 0.f;
    for (int i = 0; i < 512; ++i) {
        s += P1[(size_t)i * 128 + m];
        q += P1[(size_t)i * 128 + 64 + m];
    }
    const float inv = 1.f / (float)(B_ * N_ * K_);
    const float mu  = s * inv;
    const float var = q * inv - mu * mu;
    const float rs  = rsqrtf(var + 1e-5f);
    const float sc  = gamma1[m] * rs;
    sc1[m] = sc;
    sh1[m] = beta1[m] - mu * sc;
}

/* ------------------------------------------------------------------ */
/* Pass 4: hbn = leaky(bn1(max_k h)) fused at load; h2 = hbn @ W2^T -> d_out raw.
   grid (128,4): 64 rows x 128 d per block. Also per-block partial sums of h2 per d. */
__global__ __launch_bounds__(256) void k_gemm2(const float* __restrict__ Hmax,
                                               const float* __restrict__ Hmin,
                                               const float* __restrict__ sc1,
                                               const float* __restrict__ sh1,
                                               const float* __restrict__ W2,
                                               float* __restrict__ out,
                                               float* __restrict__ P2s,
                                               float* __restrict__ P2q) {
    __shared__ __align__(16) float sH[64][68];
    __shared__ __align__(16) float sW2[128][68];
    __shared__ float sRs[16][128];
    __shared__ float sRq[16][128];
    const int t  = threadIdx.x;
    const int tx = t & 15, ty = t >> 4;
    const int r0 = blockIdx.x * 64, d0 = blockIdx.y * 128;

    {
        const float4 sc4 = *(const float4*)&sc1[tx * 4];
        const float4 sh4 = *(const float4*)&sh1[tx * 4];
#pragma unroll
        for (int i = 0; i < 4; ++i) {
            const int row = ty + 16 * i;
            const float4 hx = *(const float4*)&Hmax[(size_t)(r0 + row) * 64 + tx * 4];
            const float4 hn = *(const float4*)&Hmin[(size_t)(r0 + row) * 64 + tx * 4];
            float v0 = (sc4.x >= 0.f ? hx.x : hn.x) * sc4.x + sh4.x;
            float v1 = (sc4.y >= 0.f ? hx.y : hn.y) * sc4.y + sh4.y;
            float v2 = (sc4.z >= 0.f ? hx.z : hn.z) * sc4.z + sh4.z;
            float v3 = (sc4.w >= 0.f ? hx.w : hn.w) * sc4.w + sh4.w;
            v0 = v0 >= 0.f ? v0 : 0.2f * v0;
            v1 = v1 >= 0.f ? v1 : 0.2f * v1;
            v2 = v2 >= 0.f ? v2 : 0.2f * v2;
            v3 = v3 >= 0.f ? v3 : 0.2f * v3;
            float4 vv; vv.x = v0; vv.y = v1; vv.z = v2; vv.w = v3;
            *(float4*)&sH[row][tx * 4] = vv;
        }
    }
#pragma unroll
    for (int i = 0; i < 8; ++i) {
        const int d = ty + 16 * i;
        *(float4*)&sW2[d][tx * 4] =
            *(const float4*)&W2[(size_t)(d0 + d) * 64 + tx * 4];
    }
    __syncthreads();

    float acc[4][8];
#pragma unroll
    for (int a = 0; a < 4; ++a)
#pragma unroll
        for (int b = 0; b < 8; ++b) acc[a][b] = 0.f;

#pragma unroll
    for (int m4 = 0; m4 < 16; ++m4) {
        float4 a[4];
#pragma unroll
        for (int rr = 0; rr < 4; ++rr) a[rr] = *(const float4*)&sH[4 * ty + rr][m4 * 4];
#pragma unroll
        for (int jj = 0; jj < 8; ++jj) {
            const float4 bb = *(const float4*)&sW2[tx + 16 * jj][m4 * 4];
#pragma unroll
            for (int rr = 0; rr < 4; ++rr)
                acc[rr][jj] += a[rr].x * bb.x + a[rr].y * bb.y + a[rr].z * bb.z + a[rr].w * bb.w;
        }
    }

#pragma unroll
    for (int rr = 0; rr < 4; ++rr)
#pragma unroll
        for (int jj = 0; jj < 8; ++jj)
            out[(size_t)(r0 + 4 * ty + rr) * 512 + d0 + tx + 16 * jj] = acc[rr][jj];

    float psum[8], psq[8];
#pragma unroll
    for (int jj = 0; jj < 8; ++jj) {
        psum[jj] = acc[0][jj] + acc[1][jj] + acc[2][jj] + acc[3][jj];
        psq[jj]  = acc[0][jj]*acc[0][jj] + acc[1][jj]*acc[1][jj]
                 + acc[2][jj]*acc[2][jj] + acc[3][jj]*acc[3][jj];
    }
#pragma unroll
    for (int jj = 0; jj < 8; ++jj) {
        sRs[ty][tx + 16 * jj] = psum[jj];
        sRq[ty][tx + 16 * jj] = psq[jj];
    }
    __syncthreads();
    if (t < 128) {
        float s = 0.f, q = 0.f;
#pragma unroll
        for (int i = 0; i < 16; ++i) { s += sRs[i][t]; q += sRq[i][t]; }
        P2s[(size_t)blockIdx.x * 512 + d0 + t] = s;
        P2q[(size_t)blockIdx.x * 512 + d0 + t] = q;
    }
}

/* ------------------------------------------------------------------ */
__global__ void k_stats2(const float* __restrict__ P2s,
                         const float* __restrict__ P2q,
                         const float* __restrict__ gamma2,
                         const float* __restrict__ beta2,
                         float* __restrict__ sc2,
                         float* __restrict__ sh2) {
    const int d = blockIdx.x * 256 + threadIdx.x;  /* 512 total */
    float s = 0.f, q = 0.f;
    for (int i = 0; i < 128; ++i) {
        s += P2s[(size_t)i * 512 + d];
        q += P2q[(size_t)i * 512 + d];
    }
    const float inv = 1.f / (float)R_;
    const float mu  = s * inv;
    const float var = q * inv - mu * mu;
    const float rs  = rsqrtf(var + 1e-5f);
    const float sc  = gamma2[d] * rs;
    sc2[d] = sc;
    sh2[d] = beta2[d] - mu * sc;
}

/* ------------------------------------------------------------------ */
__global__ __launch_bounds__(256) void k_apply(float* __restrict__ out,
                                               const float* __restrict__ sc2,
                                               const float* __restrict__ sh2) {
    const int total4 = R_ * C_ / 4;
    for (int i = blockIdx.x * 256 + threadIdx.x; i < total4; i += gridDim.x * 256) {
        float4 v = *(float4*)&out[(size_t)i * 4];
        const int d0 = (i * 4) & 511;
        const float4 sc = *(const float4*)&sc2[d0];
        const float4 sh = *(const float4*)&sh2[d0];
        v.x = v.x * sc.x + sh.x;
        v.y = v.y * sc.y + sh.y;
        v.z = v.z * sc.z + sh.z;
        v.w = v.w * sc.w + sh.w;
        v.x = v.x >= 0.f ? v.x : 0.2f * v.x;
        v.y = v.y >= 0.f ? v.y : 0.2f * v.y;
        v.z = v.z >= 0.f ? v.z : 0.2f * v.z;
        v.w = v.w >= 0.f ? v.w : 0.2f * v.w;
        *(float4*)&out[(size_t)i * 4] = v;
    }
}

/* ------------------------------------------------------------------ */
extern "C" void kernel_launch(void* const* d_in, const int* in_sizes, int n_in,
                              void* d_out, int out_size, void* d_ws, size_t ws_size,
                              hipStream_t stream) {
    const float* x   = (const float*)d_in[0];
    const int*   idx = (const int*)d_in[1];
    const float* W1  = (const float*)d_in[2];
    const float* g1  = (const float*)d_in[3];
    const float* b1  = (const float*)d_in[4];
    const float* W2  = (const float*)d_in[5];
    const float* g2  = (const float*)d_in[6];
    const float* b2  = (const float*)d_in[7];
    float* out = (float*)d_out;
    float* ws  = (float*)d_ws;

    float* Y    = ws + WS_Y;
    float* Hmax = ws + WS_HMAX;
    float* Hmin = ws + WS_HMIN;
    float* P1   = ws + WS_P1;
    float* sc1  = ws + WS_SC1;
    float* sh1  = ws + WS_SH1;
    float* P2s  = ws + WS_P2S;
    float* P2q  = ws + WS_P2Q;
    float* sc2  = ws + WS_SC2;
    float* sh2  = ws + WS_SH2;

    k_yz<<<dim3(R_ / 32), dim3(256), 0, stream>>>(x, W1, Y);
    k_gather<<<dim3(R_ / 16), dim3(256), 0, stream>>>(Y, idx, Hmax, Hmin, P1);
    k_stats1<<<dim3(1), dim3(64), 0, stream>>>(P1, g1, b1, sc1, sh1);
    k_gemm2<<<dim3(R_ / 64, 4), dim3(256), 0, stream>>>(Hmax, Hmin, sc1, sh1, W2, out, P2s, P2q);
    k_stats2<<<dim3(2), dim3(256), 0, stream>>>(P2s, P2q, g2, b2, sc2, sh2);
    k_apply<<<dim3(1024), dim3(256), 0, stream>>>(out, sc2, sh2);
}

// Round 2
// 82.895 us; speedup vs baseline: 1.0190x; 1.0190x over previous
//
#include <hip/hip_runtime.h>
#include <math.h>

#define B_ 8
#define N_ 1024
#define C_ 512
#define K_ 20
#define M_ 64
#define R_ (B_*N_)   /* 8192 points */

typedef short bf16x8 __attribute__((ext_vector_type(8)));
typedef float f32x4  __attribute__((ext_vector_type(4)));

/* ---- workspace layout (in floats) ---- */
#define WS_Y      0                       /* R_*128 : y (m<64) || z (m>=64) per point */
#define WS_HMAX   (R_*128)                /* R_*64 */
#define WS_HMIN   (WS_HMAX + R_*64)      /* R_*64 */
#define WS_P1     (WS_HMIN + R_*64)      /* 512 blocks * 128 (sum||sumsq) */
#define WS_SC1    (WS_P1 + 512*128)      /* 64 */
#define WS_SH1    (WS_SC1 + 64)          /* 64 */
#define WS_P2S    (WS_SH1 + 64)          /* 128*512 */
#define WS_P2Q    (WS_P2S + 128*512)     /* 128*512 */
#define WS_SC2    (WS_P2Q + 128*512)     /* 512 */
#define WS_SH2    (WS_SC2 + 512)         /* 512 */

__device__ __forceinline__ uint f2b(float f) {
    union { float f; uint u; } v; v.f = f;
    return (v.u + 0x7fffu + ((v.u >> 16) & 1u)) >> 16;
}
__device__ __forceinline__ uint2 f4_to_b4(float4 v) {
    uint2 r;
    r.x = f2b(v.x) | (f2b(v.y) << 16);
    r.y = f2b(v.z) | (f2b(v.w) << 16);
    return r;
}

/* ------------------------------------------------------------------ */
/* Pass 1 (bf16 MFMA): Y[r][j]; j<64: x[r]·W1[j,0:512]; j>=64: x[r]·W1[j-64,512:1024].
   Block: 32 rows x 128 cols, 4 waves (2 row x 2 col), wave tile 16x64.
   K-chunks of 64, prefetch next chunk into regs during MFMA phase. */
__global__ __launch_bounds__(256) void k_yz(const float* __restrict__ x,
                                            const float* __restrict__ W1,
                                            float* __restrict__ Y) {
    __shared__ __align__(16) ushort sXb[32][72];   /* pad 72: +16B stagger */
    __shared__ __align__(16) ushort sWb[128][72];
    const int t  = threadIdx.x;
    const int r0 = blockIdx.x * 32;
    const int lane = t & 63, wid = t >> 6;
    const int wr = wid >> 1, wc = wid & 1;

    /* staging geometry */
    const int c    = t & 15;          /* float4 column within 64-k chunk */
    const int row0 = t >> 4;          /* x rows: row0, row0+16 */
    /* W1 source bases for j = row0 + 16*i, i=0..7 */
    size_t wbase[8];
#pragma unroll
    for (int i = 0; i < 8; ++i) {
        const int j = row0 + 16 * i;
        wbase[i] = (j < 64 ? (size_t)j * 1024 : (size_t)(j - 64) * 1024 + 512) + c * 4;
    }
    const size_t xbase0 = (size_t)(r0 + row0) * 512 + c * 4;
    const size_t xbase1 = xbase0 + (size_t)16 * 512;

    f32x4 acc[4];
#pragma unroll
    for (int jj = 0; jj < 4; ++jj) acc[jj] = (f32x4){0.f, 0.f, 0.f, 0.f};

    const ushort* pA  = &sXb[wr * 16 + (lane & 15)][(lane >> 4) * 8];
    const ushort* pB0 = &sWb[wc * 64 + (lane & 15)][(lane >> 4) * 8];
    uint2* dX0 = (uint2*)&sXb[row0][c * 4];
    uint2* dX1 = (uint2*)&sXb[row0 + 16][c * 4];

    /* prefetch chunk 0 */
    float4 xr0 = *(const float4*)&x[xbase0];
    float4 xr1 = *(const float4*)&x[xbase1];
    float4 w1r[8];
#pragma unroll
    for (int i = 0; i < 8; ++i) w1r[i] = *(const float4*)&W1[wbase[i]];

    for (int ks = 0; ks < 8; ++ks) {
        __syncthreads();
        *dX0 = f4_to_b4(xr0);
        *dX1 = f4_to_b4(xr1);
#pragma unroll
        for (int i = 0; i < 8; ++i)
            *(uint2*)&sWb[row0 + 16 * i][c * 4] = f4_to_b4(w1r[i]);
        __syncthreads();

        if (ks < 7) {
            const int k0 = (ks + 1) * 64;
            xr0 = *(const float4*)&x[xbase0 + k0];
            xr1 = *(const float4*)&x[xbase1 + k0];
#pragma unroll
            for (int i = 0; i < 8; ++i)
                w1r[i] = *(const float4*)&W1[wbase[i] + k0];
        }

#pragma unroll
        for (int g = 0; g < 2; ++g) {
            const bf16x8 af = *(const bf16x8*)(pA + g * 32);
#pragma unroll
            for (int jj = 0; jj < 4; ++jj) {
                const bf16x8 bf = *(const bf16x8*)(pB0 + jj * 16 * 72 + g * 32);
                acc[jj] = __builtin_amdgcn_mfma_f32_16x16x32_bf16(af, bf, acc[jj], 0, 0, 0);
            }
        }
    }

    /* C/D layout: col = lane&15, row = (lane>>4)*4 + reg  */
    const int crow = r0 + wr * 16 + (lane >> 4) * 4;
    const int ccol = wc * 64 + (lane & 15);
#pragma unroll
    for (int jj = 0; jj < 4; ++jj)
#pragma unroll
        for (int i = 0; i < 4; ++i)
            Y[(size_t)(crow + i) * 128 + ccol + jj * 16] = acc[jj][i];
}

/* ------------------------------------------------------------------ */
/* Pass 2: gather + h stats + per-point max/min over k. */
__global__ __launch_bounds__(256) void k_gather(const float* __restrict__ Y,
                                                const int* __restrict__ idx,
                                                float* __restrict__ Hmax,
                                                float* __restrict__ Hmin,
                                                float* __restrict__ P1) {
    __shared__ float sRed[4][128];
    const int t = threadIdx.x;
    const int w = t >> 6, lane = t & 63;
    const int p0 = blockIdx.x * 16 + w * 4;
    float s_sum = 0.f, s_sq = 0.f;
#pragma unroll
    for (int i = 0; i < 4; ++i) {
        const int p = p0 + i;
        const int b = p >> 10;           /* N_=1024 */
        const float ys = Y[(size_t)p * 128 + lane];
        const float zs = Y[(size_t)p * 128 + 64 + lane];
        const float base = zs - ys;
        float hmx = -INFINITY, hmn = INFINITY;
        const int* ip = &idx[p * K_];
#pragma unroll
        for (int k = 0; k < K_; ++k) {
            const int j = ip[k];
            const float yg = Y[((size_t)(b * N_ + j)) * 128 + lane];
            const float h = yg + base;
            s_sum += h;
            s_sq  += h * h;
            hmx = fmaxf(hmx, h);
            hmn = fminf(hmn, h);
        }
        Hmax[(size_t)p * 64 + lane] = hmx;
        Hmin[(size_t)p * 64 + lane] = hmn;
    }
    sRed[w][lane]      = s_sum;
    sRed[w][64 + lane] = s_sq;
    __syncthreads();
    if (t < 128) {
        const float v = sRed[0][t] + sRed[1][t] + sRed[2][t] + sRed[3][t];
        P1[(size_t)blockIdx.x * 128 + t] = v;
    }
}

/* ------------------------------------------------------------------ */
__global__ __launch_bounds__(256) void k_stats1(const float* __restrict__ P1,
                         const float* __restrict__ gamma1,
                         const float* __restrict__ beta1,
                         float* __restrict__ sc1,
                         float* __restrict__ sh1) {
    __shared__ float sS[256], sQ[256];
    const int t = threadIdx.x;
    const int m = t & 63, cpart = t >> 6;
    float s = 0.f, q = 0.f;
    for (int i = cpart * 128; i < cpart * 128 + 128; ++i) {
        s += P1[(size_t)i * 128 + m];
        q += P1[(size_t)i * 128 + 64 + m];
    }
    sS[t] = s; sQ[t] = q;
    __syncthreads();
    if (t < 64) {
        s = sS[t] + sS[t + 64] + sS[t + 128] + sS[t + 192];
        q = sQ[t] + sQ[t + 64] + sQ[t + 128] + sQ[t + 192];
        const float inv = 1.f / (float)(B_ * N_ * K_);
        const float mu  = s * inv;
        const float var = q * inv - mu * mu;
        const float rs  = rsqrtf(var + 1e-5f);
        const float sc  = gamma1[t] * rs;
        sc1[t] = sc;
        sh1[t] = beta1[t] - mu * sc;
    }
}

/* ------------------------------------------------------------------ */
/* Pass 4: hbn = leaky(bn1(max_k h)) fused at load; h2 = hbn @ W2^T -> d_out raw. */
__global__ __launch_bounds__(256) void k_gemm2(const float* __restrict__ Hmax,
                                               const float* __restrict__ Hmin,
                                               const float* __restrict__ sc1,
                                               const float* __restrict__ sh1,
                                               const float* __restrict__ W2,
                                               float* __restrict__ out,
                                               float* __restrict__ P2s,
                                               float* __restrict__ P2q) {
    __shared__ __align__(16) float sH[64][68];
    __shared__ __align__(16) float sW2[128][68];
    __shared__ float sRs[16][128];
    __shared__ float sRq[16][128];
    const int t  = threadIdx.x;
    const int tx = t & 15, ty = t >> 4;
    const int r0 = blockIdx.x * 64, d0 = blockIdx.y * 128;

    {
        const float4 sc4 = *(const float4*)&sc1[tx * 4];
        const float4 sh4 = *(const float4*)&sh1[tx * 4];
#pragma unroll
        for (int i = 0; i < 4; ++i) {
            const int row = ty + 16 * i;
            const float4 hx = *(const float4*)&Hmax[(size_t)(r0 + row) * 64 + tx * 4];
            const float4 hn = *(const float4*)&Hmin[(size_t)(r0 + row) * 64 + tx * 4];
            float v0 = (sc4.x >= 0.f ? hx.x : hn.x) * sc4.x + sh4.x;
            float v1 = (sc4.y >= 0.f ? hx.y : hn.y) * sc4.y + sh4.y;
            float v2 = (sc4.z >= 0.f ? hx.z : hn.z) * sc4.z + sh4.z;
            float v3 = (sc4.w >= 0.f ? hx.w : hn.w) * sc4.w + sh4.w;
            v0 = v0 >= 0.f ? v0 : 0.2f * v0;
            v1 = v1 >= 0.f ? v1 : 0.2f * v1;
            v2 = v2 >= 0.f ? v2 : 0.2f * v2;
            v3 = v3 >= 0.f ? v3 : 0.2f * v3;
            float4 vv; vv.x = v0; vv.y = v1; vv.z = v2; vv.w = v3;
            *(float4*)&sH[row][tx * 4] = vv;
        }
    }
#pragma unroll
    for (int i = 0; i < 8; ++i) {
        const int d = ty + 16 * i;
        *(float4*)&sW2[d][tx * 4] =
            *(const float4*)&W2[(size_t)(d0 + d) * 64 + tx * 4];
    }
    __syncthreads();

    float acc[4][8];
#pragma unroll
    for (int a = 0; a < 4; ++a)
#pragma unroll
        for (int b = 0; b < 8; ++b) acc[a][b] = 0.f;

#pragma unroll
    for (int m4 = 0; m4 < 16; ++m4) {
        float4 a[4];
#pragma unroll
        for (int rr = 0; rr < 4; ++rr) a[rr] = *(const float4*)&sH[4 * ty + rr][m4 * 4];
#pragma unroll
        for (int jj = 0; jj < 8; ++jj) {
            const float4 bb = *(const float4*)&sW2[tx + 16 * jj][m4 * 4];
#pragma unroll
            for (int rr = 0; rr < 4; ++rr)
                acc[rr][jj] += a[rr].x * bb.x + a[rr].y * bb.y + a[rr].z * bb.z + a[rr].w * bb.w;
        }
    }

#pragma unroll
    for (int rr = 0; rr < 4; ++rr)
#pragma unroll
        for (int jj = 0; jj < 8; ++jj)
            out[(size_t)(r0 + 4 * ty + rr) * 512 + d0 + tx + 16 * jj] = acc[rr][jj];

    float psum[8], psq[8];
#pragma unroll
    for (int jj = 0; jj < 8; ++jj) {
        psum[jj] = acc[0][jj] + acc[1][jj] + acc[2][jj] + acc[3][jj];
        psq[jj]  = acc[0][jj]*acc[0][jj] + acc[1][jj]*acc[1][jj]
                 + acc[2][jj]*acc[2][jj] + acc[3][jj]*acc[3][jj];
    }
#pragma unroll
    for (int jj = 0; jj < 8; ++jj) {
        sRs[ty][tx + 16 * jj] = psum[jj];
        sRq[ty][tx + 16 * jj] = psq[jj];
    }
    __syncthreads();
    if (t < 128) {
        float s = 0.f, q = 0.f;
#pragma unroll
        for (int i = 0; i < 16; ++i) { s += sRs[i][t]; q += sRq[i][t]; }
        P2s[(size_t)blockIdx.x * 512 + d0 + t] = s;
        P2q[(size_t)blockIdx.x * 512 + d0 + t] = q;
    }
}

/* ------------------------------------------------------------------ */
__global__ void k_stats2(const float* __restrict__ P2s,
                         const float* __restrict__ P2q,
                         const float* __restrict__ gamma2,
                         const float* __restrict__ beta2,
                         float* __restrict__ sc2,
                         float* __restrict__ sh2) {
    const int d = blockIdx.x * 256 + threadIdx.x;  /* 512 total */
    float s = 0.f, q = 0.f;
    for (int i = 0; i < 128; ++i) {
        s += P2s[(size_t)i * 512 + d];
        q += P2q[(size_t)i * 512 + d];
    }
    const float inv = 1.f / (float)R_;
    const float mu  = s * inv;
    const float var = q * inv - mu * mu;
    const float rs  = rsqrtf(var + 1e-5f);
    const float sc  = gamma2[d] * rs;
    sc2[d] = sc;
    sh2[d] = beta2[d] - mu * sc;
}

/* ------------------------------------------------------------------ */
__global__ __launch_bounds__(256) void k_apply(float* __restrict__ out,
                                               const float* __restrict__ sc2,
                                               const float* __restrict__ sh2) {
    const int total4 = R_ * C_ / 4;
    for (int i = blockIdx.x * 256 + threadIdx.x; i < total4; i += gridDim.x * 256) {
        float4 v = *(float4*)&out[(size_t)i * 4];
        const int d0 = (i * 4) & 511;
        const float4 sc = *(const float4*)&sc2[d0];
        const float4 sh = *(const float4*)&sh2[d0];
        v.x = v.x * sc.x + sh.x;
        v.y = v.y * sc.y + sh.y;
        v.z = v.z * sc.z + sh.z;
        v.w = v.w * sc.w + sh.w;
        v.x = v.x >= 0.f ? v.x : 0.2f * v.x;
        v.y = v.y >= 0.f ? v.y : 0.2f * v.y;
        v.z = v.z >= 0.f ? v.z : 0.2f * v.z;
        v.w = v.w >= 0.f ? v.w : 0.2f * v.w;
        *(float4*)&out[(size_t)i * 4] = v;
    }
}

/* ------------------------------------------------------------------ */
extern "C" void kernel_launch(void* const* d_in, const int* in_sizes, int n_in,
                              void* d_out, int out_size, void* d_ws, size_t ws_size,
                              hipStream_t stream) {
    const float* x   = (const float*)d_in[0];
    const int*   idx = (const int*)d_in[1];
    const float* W1  = (const float*)d_in[2];
    const float* g1  = (const float*)d_in[3];
    const float* b1  = (const float*)d_in[4];
    const float* W2  = (const float*)d_in[5];
    const float* g2  = (const float*)d_in[6];
    const float* b2  = (const float*)d_in[7];
    float* out = (float*)d_out;
    float* ws  = (float*)d_ws;

    float* Y    = ws + WS_Y;
    float* Hmax = ws + WS_HMAX;
    float* Hmin = ws + WS_HMIN;
    float* P1   = ws + WS_P1;
    float* sc1  = ws + WS_SC1;
    float* sh1  = ws + WS_SH1;
    float* P2s  = ws + WS_P2S;
    float* P2q  = ws + WS_P2Q;
    float* sc2  = ws + WS_SC2;
    float* sh2  = ws + WS_SH2;

    k_yz<<<dim3(R_ / 32), dim3(256), 0, stream>>>(x, W1, Y);
    k_gather<<<dim3(R_ / 16), dim3(256), 0, stream>>>(Y, idx, Hmax, Hmin, P1);
    k_stats1<<<dim3(1), dim3(256), 0, stream>>>(P1, g1, b1, sc1, sh1);
    k_gemm2<<<dim3(R_ / 64, 4), dim3(256), 0, stream>>>(Hmax, Hmin, sc1, sh1, W2, out, P2s, P2q);
    k_stats2<<<dim3(2), dim3(256), 0, stream>>>(P2s, P2q, g2, b2, sc2, sh2);
    k_apply<<<dim3(1024), dim3(256), 0, stream>>>(out, sc2, sh2);
}

// Round 3
// 63.672 us; speedup vs baseline: 1.3267x; 1.3019x over previous
//
#include <hip/hip_runtime.h>
#include <math.h>

#define B_ 8
#define N_ 1024
#define C_ 512
#define K_ 20
#define M_ 64
#define R_ (B_*N_)   /* 8192 points */

typedef short bf16x8 __attribute__((ext_vector_type(8)));
typedef float f32x4  __attribute__((ext_vector_type(4)));

/* ---- workspace layout (floats) ---- */
#define WS_Y     0                       /* R_*128 fp32 */
#define WS_HMAX  (WS_Y + R_*128)         /* R_*64 */
#define WS_HMIN  (WS_HMAX + R_*64)       /* R_*64 */
#define WS_P1    (WS_HMIN + R_*64)       /* 1024*128 */
#define WS_SC1   (WS_P1 + 1024*128)      /* 64 */
#define WS_SH1   (WS_SC1 + 64)           /* 64 */
#define WS_HB    (WS_SH1 + 64)           /* R_*64 bf16 = R_*32 floats */
#define WS_W1B   (WS_HB + R_*32)         /* 128*512 bf16 = 32768 floats */
#define WS_W2B   (WS_W1B + 32768)        /* 512*64 bf16 = 16384 floats */
#define WS_P2S   (WS_W2B + 16384)        /* 128*512 */
#define WS_P2Q   (WS_P2S + 128*512)      /* 128*512 */
#define WS_SC2   (WS_P2Q + 128*512)      /* 512 */
#define WS_SH2   (WS_SC2 + 512)          /* 512 */

__device__ __forceinline__ uint f2b(float f) {
    union { float f; uint u; } v; v.f = f;
    return (v.u + 0x7fffu + ((v.u >> 16) & 1u)) >> 16;
}
__device__ __forceinline__ uint2 f4_to_b4(float4 v) {
    uint2 r;
    r.x = f2b(v.x) | (f2b(v.y) << 16);
    r.y = f2b(v.z) | (f2b(v.w) << 16);
    return r;
}
__device__ __forceinline__ float lrelu(float v) { return v >= 0.f ? v : 0.2f * v; }

/* ------------------------------------------------------------------ */
/* Pre-convert W1 (with half-split remap) and W2 to bf16, once. */
__global__ __launch_bounds__(256) void k_cvtW(const float* __restrict__ W1,
                                              const float* __restrict__ W2,
                                              ushort* __restrict__ W1b,
                                              ushort* __restrict__ W2b) {
    const int tid = blockIdx.x * 256 + threadIdx.x;
    if (tid < 8192) {                       /* W1b: 128 rows x 512 */
        const int o = tid * 8, j = o >> 9, k = o & 511;
        const float* src = (j < 64) ? &W1[(size_t)j * 1024 + k]
                                    : &W1[(size_t)(j - 64) * 1024 + 512 + k];
        const float4 a = *(const float4*)src;
        const float4 b = *(const float4*)(src + 4);
        const uint2 la = f4_to_b4(a), lb = f4_to_b4(b);
        uint4 v; v.x = la.x; v.y = la.y; v.z = lb.x; v.w = lb.y;
        ((uint4*)W1b)[tid] = v;
    } else if (tid < 12288) {               /* W2b: 512 rows x 64 */
        const int t2 = tid - 8192, o = t2 * 8;
        const float4 a = *(const float4*)&W2[o];
        const float4 b = *(const float4*)&W2[o + 4];
        const uint2 la = f4_to_b4(a), lb = f4_to_b4(b);
        uint4 v; v.x = la.x; v.y = la.y; v.z = lb.x; v.w = lb.y;
        ((uint4*)W2b)[t2] = v;
    }
}

/* ------------------------------------------------------------------ */
/* Y[r][j] = x[r] . W1b[j]   (16 rows x 128 cols per block, 512 blocks) */
__global__ __launch_bounds__(256) void k_yz(const float* __restrict__ x,
                                            const ushort* __restrict__ W1b,
                                            float* __restrict__ Y) {
    __shared__ __align__(16) ushort sXb[16][72];
    __shared__ __align__(16) ushort sWb[128][72];
    const int t = threadIdx.x, lane = t & 63, w = t >> 6;
    const int r0 = blockIdx.x * 16;
    const int xr_row = t >> 4, xc = t & 15;
    const int wj = t >> 1, wh = t & 1;
    const size_t xbase = (size_t)(r0 + xr_row) * 512 + xc * 4;
    const size_t wbase = (size_t)wj * 512 + wh * 32;

    f32x4 acc[2];
    acc[0] = (f32x4){0.f, 0.f, 0.f, 0.f};
    acc[1] = (f32x4){0.f, 0.f, 0.f, 0.f};

    const ushort* pA  = &sXb[lane & 15][(lane >> 4) * 8];
    const ushort* pB0 = &sWb[w * 32 + (lane & 15)][(lane >> 4) * 8];

    float4 xr = *(const float4*)&x[xbase];
    uint4 wv[4];
#pragma unroll
    for (int i = 0; i < 4; ++i) wv[i] = *(const uint4*)&W1b[wbase + i * 8];

    for (int ks = 0; ks < 8; ++ks) {
        __syncthreads();
        *(uint2*)&sXb[xr_row][xc * 4] = f4_to_b4(xr);
#pragma unroll
        for (int i = 0; i < 4; ++i)
            *(uint4*)&sWb[wj][wh * 32 + i * 8] = wv[i];
        __syncthreads();

        if (ks < 7) {
            const int k0 = (ks + 1) * 64;
            xr = *(const float4*)&x[xbase + k0];
#pragma unroll
            for (int i = 0; i < 4; ++i)
                wv[i] = *(const uint4*)&W1b[wbase + k0 + i * 8];
        }

#pragma unroll
        for (int g = 0; g < 2; ++g) {
            const bf16x8 af = *(const bf16x8*)(pA + g * 32);
#pragma unroll
            for (int jj = 0; jj < 2; ++jj) {
                const bf16x8 bf = *(const bf16x8*)(pB0 + jj * 16 * 72 + g * 32);
                acc[jj] = __builtin_amdgcn_mfma_f32_16x16x32_bf16(af, bf, acc[jj], 0, 0, 0);
            }
        }
    }

    const int crow = r0 + (lane >> 4) * 4;
    const int ccol = w * 32 + (lane & 15);
#pragma unroll
    for (int jj = 0; jj < 2; ++jj)
#pragma unroll
        for (int i = 0; i < 4; ++i)
            Y[(size_t)(crow + i) * 128 + ccol + jj * 16] = acc[jj][i];
}

/* ------------------------------------------------------------------ */
/* gather + per-point max/min + BN1 partial sums. 1024 blocks, 2 pts/wave */
__global__ __launch_bounds__(256) void k_gather(const float* __restrict__ Y,
                                                const int* __restrict__ idx,
                                                float* __restrict__ Hmax,
                                                float* __restrict__ Hmin,
                                                float* __restrict__ P1) {
    __shared__ float sRed[4][128];
    const int t = threadIdx.x;
    const int w = t >> 6, lane = t & 63;
    const int p0 = blockIdx.x * 8 + w * 2;
    float s_sum = 0.f, s_sq = 0.f;
#pragma unroll
    for (int i = 0; i < 2; ++i) {
        const int p = p0 + i;
        const int b = p >> 10;
        const float ys = Y[(size_t)p * 128 + lane];
        const float zs = Y[(size_t)p * 128 + 64 + lane];
        const float base = zs - ys;
        float hmx = -INFINITY, hmn = INFINITY;
        const int* ip = &idx[p * K_];
#pragma unroll
        for (int k = 0; k < K_; ++k) {
            const int j = ip[k];
            const float yg = Y[((size_t)(b * N_ + j)) * 128 + lane];
            const float h = yg + base;
            s_sum += h;
            s_sq  += h * h;
            hmx = fmaxf(hmx, h);
            hmn = fminf(hmn, h);
        }
        Hmax[(size_t)p * 64 + lane] = hmx;
        Hmin[(size_t)p * 64 + lane] = hmn;
    }
    sRed[w][lane]      = s_sum;
    sRed[w][64 + lane] = s_sq;
    __syncthreads();
    if (t < 128) {
        P1[(size_t)blockIdx.x * 128 + t] =
            sRed[0][t] + sRed[1][t] + sRed[2][t] + sRed[3][t];
    }
}

/* ------------------------------------------------------------------ */
/* reduce P1 (1024 x 128) -> sc1/sh1 [64].  1 block x 1024 threads. */
__global__ __launch_bounds__(1024) void k_stats1(const float* __restrict__ P1,
                                                 const float* __restrict__ gamma1,
                                                 const float* __restrict__ beta1,
                                                 float* __restrict__ sc1,
                                                 float* __restrict__ sh1) {
    __shared__ float sP[1024];
    __shared__ float sT[128];
    const int t = threadIdx.x;
    const int col = t & 127, part = t >> 7;   /* 8 parts x 128 rows */
    float s = 0.f;
#pragma unroll 8
    for (int i = 0; i < 128; ++i)
        s += P1[(size_t)(part * 128 + i) * 128 + col];
    sP[t] = s;
    __syncthreads();
    if (t < 128) {
        float v = 0.f;
#pragma unroll
        for (int p = 0; p < 8; ++p) v += sP[p * 128 + t];
        sT[t] = v;
    }
    __syncthreads();
    if (t < 64) {
        const float inv = 1.f / (float)(B_ * N_ * K_);
        const float mu  = sT[t] * inv;
        const float var = sT[t + 64] * inv - mu * mu;
        const float rs  = rsqrtf(var + 1e-5f);
        const float sc  = gamma1[t] * rs;
        sc1[t] = sc;
        sh1[t] = beta1[t] - mu * sc;
    }
}

/* ------------------------------------------------------------------ */
/* hbn = leaky(bn1(select(max,min))) -> bf16 Hb.  Elementwise. */
__global__ __launch_bounds__(256) void k_hbn(const float* __restrict__ Hmax,
                                             const float* __restrict__ Hmin,
                                             const float* __restrict__ sc1,
                                             const float* __restrict__ sh1,
                                             ushort* __restrict__ Hb) {
    __shared__ float sS[64], sH[64];
    const int t = threadIdx.x;
    if (t < 64) { sS[t] = sc1[t]; sH[t] = sh1[t]; }
    __syncthreads();
    const int tid = blockIdx.x * 256 + t;        /* 65536 chunks of 8 */
    const int m0 = (tid & 7) * 8;
    const size_t base = (size_t)(tid >> 3) * 64 + m0;
    float4 hx0 = *(const float4*)&Hmax[base];
    float4 hx1 = *(const float4*)&Hmax[base + 4];
    float4 hn0 = *(const float4*)&Hmin[base];
    float4 hn1 = *(const float4*)&Hmin[base + 4];
    float v[8];
#pragma unroll
    for (int i = 0; i < 4; ++i) {
        const float sc0 = sS[m0 + i], sh0 = sH[m0 + i];
        const float sc4 = sS[m0 + 4 + i], sh4 = sH[m0 + 4 + i];
        const float a0 = sc0 >= 0.f ? ((const float*)&hx0)[i] : ((const float*)&hn0)[i];
        const float a4 = sc4 >= 0.f ? ((const float*)&hx1)[i] : ((const float*)&hn1)[i];
        v[i]     = lrelu(a0 * sc0 + sh0);
        v[i + 4] = lrelu(a4 * sc4 + sh4);
    }
    uint4 o;
    o.x = f2b(v[0]) | (f2b(v[1]) << 16);
    o.y = f2b(v[2]) | (f2b(v[3]) << 16);
    o.z = f2b(v[4]) | (f2b(v[5]) << 16);
    o.w = f2b(v[6]) | (f2b(v[7]) << 16);
    ((uint4*)Hb)[tid] = o;
}

/* ------------------------------------------------------------------ */
/* stats-only MFMA pass: h2 = Hb @ W2b^T, accumulate per-d sum/sumsq partials.
   grid (128, 2): 64 rows x 256 d per block; wave owns a 64-d strip. */
__global__ __launch_bounds__(256) void k_qsum(const ushort* __restrict__ Hb,
                                              const ushort* __restrict__ W2b,
                                              float* __restrict__ P2s,
                                              float* __restrict__ P2q) {
    const int t = threadIdx.x, lane = t & 63, w = t >> 6;
    const int r0 = blockIdx.x * 64;
    const int dstrip = blockIdx.y * 256 + w * 64;
    const int q = lane >> 4, s = lane & 15;

    bf16x8 bfr[4][2];
#pragma unroll
    for (int f = 0; f < 4; ++f)
#pragma unroll
        for (int g = 0; g < 2; ++g)
            bfr[f][g] = *(const bf16x8*)&W2b[(size_t)(dstrip + f * 16 + s) * 64 + q * 8 + g * 32];

    f32x4 acc[4][4];
#pragma unroll
    for (int rt = 0; rt < 4; ++rt)
#pragma unroll
        for (int f = 0; f < 4; ++f) acc[rt][f] = (f32x4){0.f, 0.f, 0.f, 0.f};

#pragma unroll
    for (int rt = 0; rt < 4; ++rt)
#pragma unroll
        for (int g = 0; g < 2; ++g) {
            const bf16x8 af = *(const bf16x8*)&Hb[(size_t)(r0 + rt * 16 + s) * 64 + q * 8 + g * 32];
#pragma unroll
            for (int f = 0; f < 4; ++f)
                acc[rt][f] = __builtin_amdgcn_mfma_f32_16x16x32_bf16(af, bfr[f][g], acc[rt][f], 0, 0, 0);
        }

#pragma unroll
    for (int f = 0; f < 4; ++f) {
        float ss = 0.f, qq = 0.f;
#pragma unroll
        for (int rt = 0; rt < 4; ++rt)
#pragma unroll
            for (int i = 0; i < 4; ++i) {
                const float v = acc[rt][f][i];
                ss += v; qq += v * v;
            }
        ss += __shfl_xor(ss, 16); ss += __shfl_xor(ss, 32);
        qq += __shfl_xor(qq, 16); qq += __shfl_xor(qq, 32);
        if (lane < 16) {
            const int d = dstrip + f * 16 + s;
            P2s[(size_t)blockIdx.x * 512 + d] = ss;
            P2q[(size_t)blockIdx.x * 512 + d] = qq;
        }
    }
}

/* ------------------------------------------------------------------ */
/* reduce P2 (128 x 512) -> sc2/sh2 [512].  1 block x 1024 threads. */
__global__ __launch_bounds__(1024) void k_stats2(const float* __restrict__ P2s,
                                                 const float* __restrict__ P2q,
                                                 const float* __restrict__ gamma2,
                                                 const float* __restrict__ beta2,
                                                 float* __restrict__ sc2,
                                                 float* __restrict__ sh2) {
    __shared__ float sS[1024], sQ[1024];
    const int t = threadIdx.x;
    const int d = t & 511, part = t >> 9;    /* 2 parts x 64 rows */
    float s = 0.f, qv = 0.f;
#pragma unroll 8
    for (int i = 0; i < 64; ++i) {
        const size_t r = (size_t)(part * 64 + i) * 512 + d;
        s  += P2s[r];
        qv += P2q[r];
    }
    sS[t] = s; sQ[t] = qv;
    __syncthreads();
    if (t < 512) {
        s  = sS[t] + sS[t + 512];
        qv = sQ[t] + sQ[t + 512];
        const float inv = 1.f / (float)R_;
        const float mu  = s * inv;
        const float var = qv * inv - mu * mu;
        const float rs  = rsqrtf(var + 1e-5f);
        const float sc  = gamma2[t] * rs;
        sc2[t] = sc;
        sh2[t] = beta2[t] - mu * sc;
    }
}

/* ------------------------------------------------------------------ */
/* recompute h2 (bitwise-identical MFMA chain), apply BN2+leaky, write out. */
__global__ __launch_bounds__(256) void k_out(const ushort* __restrict__ Hb,
                                             const ushort* __restrict__ W2b,
                                             const float* __restrict__ sc2,
                                             const float* __restrict__ sh2,
                                             float* __restrict__ out) {
    const int t = threadIdx.x, lane = t & 63, w = t >> 6;
    const int r0 = blockIdx.x * 64;
    const int dstrip = blockIdx.y * 256 + w * 64;
    const int q = lane >> 4, s = lane & 15;

    bf16x8 bfr[4][2];
    float c2[4], h2s[4];
#pragma unroll
    for (int f = 0; f < 4; ++f) {
        const int d = dstrip + f * 16 + s;
        c2[f]  = sc2[d];
        h2s[f] = sh2[d];
#pragma unroll
        for (int g = 0; g < 2; ++g)
            bfr[f][g] = *(const bf16x8*)&W2b[(size_t)d * 64 + q * 8 + g * 32];
    }

    f32x4 acc[4][4];
#pragma unroll
    for (int rt = 0; rt < 4; ++rt)
#pragma unroll
        for (int f = 0; f < 4; ++f) acc[rt][f] = (f32x4){0.f, 0.f, 0.f, 0.f};

#pragma unroll
    for (int rt = 0; rt < 4; ++rt)
#pragma unroll
        for (int g = 0; g < 2; ++g) {
            const bf16x8 af = *(const bf16x8*)&Hb[(size_t)(r0 + rt * 16 + s) * 64 + q * 8 + g * 32];
#pragma unroll
            for (int f = 0; f < 4; ++f)
                acc[rt][f] = __builtin_amdgcn_mfma_f32_16x16x32_bf16(af, bfr[f][g], acc[rt][f], 0, 0, 0);
        }

#pragma unroll
    for (int rt = 0; rt < 4; ++rt)
#pragma unroll
        for (int f = 0; f < 4; ++f) {
            const int d = dstrip + f * 16 + s;
#pragma unroll
            for (int i = 0; i < 4; ++i) {
                const float v = lrelu(acc[rt][f][i] * c2[f] + h2s[f]);
                out[(size_t)(r0 + rt * 16 + q * 4 + i) * 512 + d] = v;
            }
        }
}

/* ------------------------------------------------------------------ */
extern "C" void kernel_launch(void* const* d_in, const int* in_sizes, int n_in,
                              void* d_out, int out_size, void* d_ws, size_t ws_size,
                              hipStream_t stream) {
    const float* x   = (const float*)d_in[0];
    const int*   idx = (const int*)d_in[1];
    const float* W1  = (const float*)d_in[2];
    const float* g1  = (const float*)d_in[3];
    const float* b1  = (const float*)d_in[4];
    const float* W2  = (const float*)d_in[5];
    const float* g2  = (const float*)d_in[6];
    const float* b2  = (const float*)d_in[7];
    float* out = (float*)d_out;
    float* ws  = (float*)d_ws;

    float*  Y    = ws + WS_Y;
    float*  Hmax = ws + WS_HMAX;
    float*  Hmin = ws + WS_HMIN;
    float*  P1   = ws + WS_P1;
    float*  sc1  = ws + WS_SC1;
    float*  sh1  = ws + WS_SH1;
    ushort* Hb   = (ushort*)(ws + WS_HB);
    ushort* W1b  = (ushort*)(ws + WS_W1B);
    ushort* W2b  = (ushort*)(ws + WS_W2B);
    float*  P2s  = ws + WS_P2S;
    float*  P2q  = ws + WS_P2Q;
    float*  sc2  = ws + WS_SC2;
    float*  sh2  = ws + WS_SH2;

    k_cvtW  <<<dim3(48),        dim3(256),  0, stream>>>(W1, W2, W1b, W2b);
    k_yz    <<<dim3(R_ / 16),   dim3(256),  0, stream>>>(x, W1b, Y);
    k_gather<<<dim3(R_ / 8),    dim3(256),  0, stream>>>(Y, idx, Hmax, Hmin, P1);
    k_stats1<<<dim3(1),         dim3(1024), 0, stream>>>(P1, g1, b1, sc1, sh1);
    k_hbn   <<<dim3(256),       dim3(256),  0, stream>>>(Hmax, Hmin, sc1, sh1, Hb);
    k_qsum  <<<dim3(128, 2),    dim3(256),  0, stream>>>(Hb, W2b, P2s, P2q);
    k_stats2<<<dim3(1),         dim3(1024), 0, stream>>>(P2s, P2q, g2, b2, sc2, sh2);
    k_out   <<<dim3(128, 2),    dim3(256),  0, stream>>>(Hb, W2b, sc2, sh2, out);
}